// Round 1
// baseline (362.661 us; speedup 1.0000x reference)
//
#include <hip/hip_runtime.h>
#include <hip/hip_bf16.h>
#include <stdint.h>

typedef __attribute__((ext_vector_type(8))) short short8;
typedef __attribute__((ext_vector_type(4))) float f32x4;
typedef __attribute__((ext_vector_type(4))) unsigned short u16x4;
typedef unsigned short u16;

#define EMBED 1024
#define SEQ 2048
#define NBATCH 4
#define MROWS (NBATCH * SEQ) /* 8192 */

__device__ __forceinline__ u16 f2bf(float f) {
  union { float f; uint32_t u; } v; v.f = f;
  uint32_t r = v.u + 0x7fffu + ((v.u >> 16) & 1u);
  return (u16)(r >> 16);
}

__device__ __forceinline__ void gld16(const void* g, void* l) {
  __builtin_amdgcn_global_load_lds((const __attribute__((address_space(1))) void*)g,
                                   (__attribute__((address_space(3))) void*)l, 16, 0, 0);
}

// ---------------- fp32 -> bf16 convert (vectorized) ----------------
__global__ __launch_bounds__(256) void cvt_bf16_kernel(const float4* __restrict__ in,
                                                       u16x4* __restrict__ out, int n4) {
  int stride = gridDim.x * blockDim.x;
  for (int i = blockIdx.x * blockDim.x + threadIdx.x; i < n4; i += stride) {
    float4 v = in[i];
    u16x4 o = { f2bf(v.x), f2bf(v.y), f2bf(v.z), f2bf(v.w) };
    out[i] = o;
  }
}

// ---------------- W [k][n] fp32 -> W^T [n][k] bf16 ----------------
__global__ __launch_bounds__(256) void wtrans_kernel(const float* __restrict__ W,
                                                     u16* __restrict__ Wt) {
  __shared__ float tile[32][33];
  int bx = blockIdx.x * 32, by = blockIdx.y * 32;
  int tx = threadIdx.x & 31, ty = threadIdx.x >> 5; // 32 x 8
#pragma unroll
  for (int i = 0; i < 32; i += 8)
    tile[ty + i][tx] = W[(size_t)(by + ty + i) * EMBED + bx + tx];
  __syncthreads();
#pragma unroll
  for (int i = 0; i < 32; i += 8)
    Wt[(size_t)(bx + ty + i) * EMBED + by + tx] = f2bf(tile[tx][ty + i]);
}

// ---------------- GEMM: C[M=8192][N=1024] = A[M][K=1024] * Bt[N][K]^T ----------------
// EPI 0: bf16 out, NHSD scatter ([n][h][s][d])   (Q, K)
// EPI 1: bf16 out, NHDS scatter ([n][h][d][s])   (V transposed)
// EPI 2: fp32 out row-major + bias               (final projection)
template <int EPI>
__global__ __launch_bounds__(256) void gemm_bt(const u16* __restrict__ A,
                                               const u16* __restrict__ Bt,
                                               void* __restrict__ outp,
                                               const float* __restrict__ bias) {
  constexpr int K = 1024;
  __shared__ u16 lsA[128 * 32];
  __shared__ u16 lsB[128 * 32];
  const int t = threadIdx.x, l = t & 63, w = t >> 6;
  const int g = l >> 4, r15 = l & 15;
  const int m0 = blockIdx.y * 128, n0 = blockIdx.x * 128;
  const int wm = (w >> 1) * 64, wn = (w & 1) * 64;
  f32x4 acc[4][4] = {};
  const int srow = t >> 2;        // 0..63
  const int scol = (t & 3) * 8;   // elems within 32-elem k-slice
  const u16* Ap = A + (size_t)(m0 + srow) * K + scol;
  const u16* Bp = Bt + (size_t)(n0 + srow) * K + scol;

  for (int k0 = 0; k0 < K; k0 += 32) {
    gld16(Ap + k0,            lsA + w * 512);
    gld16(Ap + k0 + 64 * K,   lsA + 2048 + w * 512);
    gld16(Bp + k0,            lsB + w * 512);
    gld16(Bp + k0 + 64 * K,   lsB + 2048 + w * 512);
    __syncthreads();
    short8 af[4], bfv[4];
#pragma unroll
    for (int mi = 0; mi < 4; ++mi)
      af[mi] = *(const short8*)&lsA[(wm + mi * 16 + r15) * 32 + g * 8];
#pragma unroll
    for (int ni = 0; ni < 4; ++ni)
      bfv[ni] = *(const short8*)&lsB[(wn + ni * 16 + r15) * 32 + g * 8];
#pragma unroll
    for (int mi = 0; mi < 4; ++mi)
#pragma unroll
      for (int ni = 0; ni < 4; ++ni)
        acc[mi][ni] = __builtin_amdgcn_mfma_f32_16x16x32_bf16(af[mi], bfv[ni], acc[mi][ni], 0, 0, 0);
    __syncthreads();
  }

#pragma unroll
  for (int mi = 0; mi < 4; ++mi)
#pragma unroll
    for (int ni = 0; ni < 4; ++ni)
#pragma unroll
      for (int r = 0; r < 4; ++r) {
        int row = m0 + wm + mi * 16 + g * 4 + r;   // D: row=(l>>4)*4+reg
        int col = n0 + wn + ni * 16 + r15;         //    col=l&15
        float v = acc[mi][ni][r];
        if (EPI == 0) {
          ((u16*)outp)[(((size_t)(row >> 11) * 16 + (col >> 6)) * SEQ + (row & 2047)) * 64 + (col & 63)] = f2bf(v);
        } else if (EPI == 1) {
          ((u16*)outp)[(((size_t)(row >> 11) * 16 + (col >> 6)) * 64 + (col & 63)) * SEQ + (row & 2047)] = f2bf(v);
        } else {
          ((float*)outp)[(size_t)row * EMBED + col] = v + bias[col];
        }
      }
}

// ---------------- flash attention ----------------
// Q, K: [bh=64][S=2048][64] bf16 ; Vt: [bh][64][S] bf16 ; out AO: [n][s][1024] bf16
__global__ __launch_bounds__(256) void attn_kernel(const u16* __restrict__ Q,
                                                   const u16* __restrict__ Kb,
                                                   const u16* __restrict__ Vt,
                                                   u16* __restrict__ AO) {
  __shared__ u16 lsK[64 * 64];
  __shared__ u16 lsV[64 * 64];
  __shared__ u16 lsP[4][16 * 72];
  const int t = threadIdx.x, l = t & 63, w = t >> 6;
  const int g = l >> 4, r15 = l & 15;
  const int q0 = blockIdx.x * 64;
  const int bh = blockIdx.y;
  const u16* Qh = Q + (size_t)bh * SEQ * 64;
  const u16* Kh = Kb + (size_t)bh * SEQ * 64;
  const u16* Vh = Vt + (size_t)bh * 64 * SEQ;

  short8 qf[2];
#pragma unroll
  for (int kh = 0; kh < 2; ++kh)
    qf[kh] = *(const short8*)&Qh[(size_t)(q0 + w * 16 + r15) * 64 + kh * 32 + g * 8];

  float mrun[4], lrun[4];
  f32x4 oacc[4] = {};
#pragma unroll
  for (int r = 0; r < 4; ++r) { mrun[r] = -1e30f; lrun[r] = 0.f; }

  const int srow = t >> 3;         // 0..31
  const int scolb = (t & 7) * 16;  // byte col within 128B row

  for (int kv0 = 0; kv0 < SEQ; kv0 += 64) {
#pragma unroll
    for (int j = 0; j < 2; ++j) {
      int row = j * 32 + srow;
      int colswz = (scolb ^ ((row & 7) << 4)) >> 1;  // pre-swizzled source (elems)
      gld16(Kh + (size_t)(kv0 + row) * 64 + colswz, lsK + j * 2048 + w * 512);
      gld16(Vh + (size_t)row * SEQ + kv0 + colswz,  lsV + j * 2048 + w * 512);
    }
    __syncthreads();

    // S = (Q K^T) * 1/sqrt(EMBED)
    f32x4 sacc[4];
#pragma unroll
    for (int c = 0; c < 4; ++c) {
      f32x4 z = {};
#pragma unroll
      for (int kh = 0; kh < 2; ++kh) {
        int row = c * 16 + r15;
        int colb = (kh * 64 + g * 16) ^ ((row & 7) << 4);
        short8 kf = *(const short8*)((const char*)lsK + row * 128 + colb);
        z = __builtin_amdgcn_mfma_f32_16x16x32_bf16(qf[kh], kf, z, 0, 0, 0);
      }
      sacc[c] = z;
    }

    float mcur[4];
#pragma unroll
    for (int r = 0; r < 4; ++r) mcur[r] = -1e30f;
#pragma unroll
    for (int c = 0; c < 4; ++c)
#pragma unroll
      for (int r = 0; r < 4; ++r) {
        sacc[c][r] *= 0.03125f;
        mcur[r] = fmaxf(mcur[r], sacc[c][r]);
      }
#pragma unroll
    for (int r = 0; r < 4; ++r)
      for (int msk = 1; msk < 16; msk <<= 1)
        mcur[r] = fmaxf(mcur[r], __shfl_xor(mcur[r], msk, 64));

    float alpha[4], rsum[4];
#pragma unroll
    for (int r = 0; r < 4; ++r) {
      float mn = fmaxf(mrun[r], mcur[r]);
      alpha[r] = __expf(mrun[r] - mn);
      mrun[r] = mn;
      rsum[r] = 0.f;
    }
#pragma unroll
    for (int c = 0; c < 4; ++c)
#pragma unroll
      for (int r = 0; r < 4; ++r) {
        float p = __expf(sacc[c][r] - mrun[r]);
        rsum[r] += p;
        lsP[w][(g * 4 + r) * 72 + c * 16 + r15] = f2bf(p);  // D-layout -> LDS
      }
#pragma unroll
    for (int r = 0; r < 4; ++r) {
      for (int msk = 1; msk < 16; msk <<= 1)
        rsum[r] += __shfl_xor(rsum[r], msk, 64);
      lrun[r] = lrun[r] * alpha[r] + rsum[r];
    }
#pragma unroll
    for (int dn = 0; dn < 4; ++dn)
#pragma unroll
      for (int r = 0; r < 4; ++r)
        oacc[dn][r] *= alpha[r];

    // O += P V   (A-frag of P from LDS transpose; B-frag of V contiguous from Vt)
#pragma unroll
    for (int dn = 0; dn < 4; ++dn) {
#pragma unroll
      for (int kh = 0; kh < 2; ++kh) {
        short8 pa = *(const short8*)&lsP[w][r15 * 72 + kh * 32 + g * 8];
        int vrow = dn * 16 + r15;
        int colb = (kh * 64 + g * 16) ^ ((vrow & 7) << 4);
        short8 vb = *(const short8*)((const char*)lsV + vrow * 128 + colb);
        oacc[dn] = __builtin_amdgcn_mfma_f32_16x16x32_bf16(pa, vb, oacc[dn], 0, 0, 0);
      }
    }
    __syncthreads();
  }

  const int nb = bh >> 4, h = bh & 15;
#pragma unroll
  for (int dn = 0; dn < 4; ++dn)
#pragma unroll
    for (int r = 0; r < 4; ++r) {
      int q = q0 + w * 16 + g * 4 + r;
      int d = dn * 16 + r15;
      float v = oacc[dn][r] / lrun[r];
      AO[((size_t)(nb * SEQ + q)) * EMBED + h * 64 + d] = f2bf(v);
    }
}

// ---------------- launch ----------------
extern "C" void kernel_launch(void* const* d_in, const int* in_sizes, int n_in,
                              void* d_out, int out_size, void* d_ws, size_t ws_size,
                              hipStream_t stream) {
  const float* values  = (const float*)d_in[0];
  const float* keys    = (const float*)d_in[1];
  const float* queries = (const float*)d_in[2];
  const float* W_v = (const float*)d_in[3];
  const float* W_k = (const float*)d_in[4];
  const float* W_q = (const float*)d_in[5];
  const float* W_o = (const float*)d_in[6];
  const float* b_o = (const float*)d_in[7];

  const size_t XSZ = (size_t)MROWS * EMBED;  // 8,388,608 elems
  const size_t WSZ = (size_t)EMBED * EMBED;  // 1,048,576 elems
  u16* ws = (u16*)d_ws;
  u16* Xv  = ws;
  u16* Xk  = ws + XSZ;
  u16* Xq  = ws + 2 * XSZ;
  u16* Wvt = ws + 3 * XSZ;
  u16* Wkt = Wvt + WSZ;
  u16* Wqt = Wkt + WSZ;
  u16* Wot = Wqt + WSZ;
  u16* Qb  = Wot + WSZ;
  u16* Kb  = Qb + XSZ;
  u16* Vtb = Kb + XSZ;
  u16* AO  = Xv;  // alias: Xv dead after V projection

  int n4 = (int)(XSZ / 4);
  cvt_bf16_kernel<<<1024, 256, 0, stream>>>((const float4*)values,  (u16x4*)Xv, n4);
  cvt_bf16_kernel<<<1024, 256, 0, stream>>>((const float4*)keys,    (u16x4*)Xk, n4);
  cvt_bf16_kernel<<<1024, 256, 0, stream>>>((const float4*)queries, (u16x4*)Xq, n4);

  dim3 tg(32, 32);
  wtrans_kernel<<<tg, 256, 0, stream>>>(W_v, Wvt);
  wtrans_kernel<<<tg, 256, 0, stream>>>(W_k, Wkt);
  wtrans_kernel<<<tg, 256, 0, stream>>>(W_q, Wqt);
  wtrans_kernel<<<tg, 256, 0, stream>>>(W_o, Wot);

  dim3 gg(EMBED / 128, MROWS / 128);  // 8 x 64
  gemm_bt<0><<<gg, 256, 0, stream>>>(Xq, Wqt, Qb, nullptr);
  gemm_bt<0><<<gg, 256, 0, stream>>>(Xk, Wkt, Kb, nullptr);
  gemm_bt<1><<<gg, 256, 0, stream>>>(Xv, Wvt, Vtb, nullptr);

  dim3 ag(SEQ / 64, NBATCH * 16);     // 32 x 64
  attn_kernel<<<ag, 256, 0, stream>>>(Qb, Kb, Vtb, AO);

  gemm_bt<2><<<gg, 256, 0, stream>>>(AO, Wot, d_out, b_o);
}

// Round 3
// 267.441 us; speedup vs baseline: 1.3560x; 1.3560x over previous
//
#include <hip/hip_runtime.h>
#include <hip/hip_bf16.h>
#include <stdint.h>

typedef __attribute__((ext_vector_type(8))) short short8;
typedef __attribute__((ext_vector_type(4))) float f32x4;
typedef __attribute__((ext_vector_type(4))) unsigned short u16x4;
typedef unsigned short u16;

#define EMBED 1024
#define SEQ 2048
#define NBATCH 4
#define MROWS (NBATCH * SEQ) /* 8192 */

__device__ __forceinline__ u16 f2bf(float f) {
  union { float f; uint32_t u; } v; v.f = f;
  uint32_t r = v.u + 0x7fffu + ((v.u >> 16) & 1u);
  return (u16)(r >> 16);
}

__device__ __forceinline__ uint32_t cvtpk(float lo, float hi) {
  uint32_t r;
  asm("v_cvt_pk_bf16_f32 %0, %1, %2" : "=v"(r) : "v"(lo), "v"(hi));
  return r;
}

__device__ __forceinline__ float exp2a(float x) {
#if __has_builtin(__builtin_amdgcn_exp2f)
  return __builtin_amdgcn_exp2f(x);
#else
  return exp2f(x);
#endif
}

__device__ __forceinline__ void gld16(const void* g, void* l) {
  __builtin_amdgcn_global_load_lds((const __attribute__((address_space(1))) void*)g,
                                   (__attribute__((address_space(3))) void*)l, 16, 0, 0);
}

// ---------------- fp32 -> bf16 convert (vectorized) ----------------
__global__ __launch_bounds__(256) void cvt_bf16_kernel(const float4* __restrict__ in,
                                                       u16x4* __restrict__ out, int n4) {
  int stride = gridDim.x * blockDim.x;
  for (int i = blockIdx.x * blockDim.x + threadIdx.x; i < n4; i += stride) {
    float4 v = in[i];
    u16x4 o = { f2bf(v.x), f2bf(v.y), f2bf(v.z), f2bf(v.w) };
    out[i] = o;
  }
}

// ---------------- W [k][n] fp32 -> W^T [n][k] bf16 ----------------
__global__ __launch_bounds__(256) void wtrans_kernel(const float* __restrict__ W,
                                                     u16* __restrict__ Wt) {
  __shared__ float tile[32][33];
  int bx = blockIdx.x * 32, by = blockIdx.y * 32;
  int tx = threadIdx.x & 31, ty = threadIdx.x >> 5; // 32 x 8
#pragma unroll
  for (int i = 0; i < 32; i += 8)
    tile[ty + i][tx] = W[(size_t)(by + ty + i) * EMBED + bx + tx];
  __syncthreads();
#pragma unroll
  for (int i = 0; i < 32; i += 8)
    Wt[(size_t)(bx + ty + i) * EMBED + by + tx] = f2bf(tile[tx][ty + i]);
}

// ---------------- GEMM: C[M=8192][N=1024] = A[M][K=1024] * Bt[N][K]^T ----------------
// EPI 0: bf16 out *oscale, NHSD scatter ([n][h][s][d])   (Q, K)
// EPI 1: bf16 out, NHDS scatter ([n][h][d][s])           (V transposed)
// EPI 2: fp32 out row-major + bias                       (final projection)
template <int EPI>
__global__ __launch_bounds__(256) void gemm_bt(const u16* __restrict__ A,
                                               const u16* __restrict__ Bt,
                                               void* __restrict__ outp,
                                               const float* __restrict__ bias,
                                               float oscale) {
  constexpr int K = 1024;
  __shared__ u16 lsA[128 * 32];
  __shared__ u16 lsB[128 * 32];
  const int t = threadIdx.x, l = t & 63, w = t >> 6;
  const int g = l >> 4, r15 = l & 15;
  const int m0 = blockIdx.y * 128, n0 = blockIdx.x * 128;
  const int wm = (w >> 1) * 64, wn = (w & 1) * 64;
  f32x4 acc[4][4] = {};
  const int srow = t >> 2;        // 0..63
  const int scol = (t & 3) * 8;   // elems within 32-elem k-slice
  const u16* Ap = A + (size_t)(m0 + srow) * K + scol;
  const u16* Bp = Bt + (size_t)(n0 + srow) * K + scol;

  for (int k0 = 0; k0 < K; k0 += 32) {
    gld16(Ap + k0,            lsA + w * 512);
    gld16(Ap + k0 + 64 * K,   lsA + 2048 + w * 512);
    gld16(Bp + k0,            lsB + w * 512);
    gld16(Bp + k0 + 64 * K,   lsB + 2048 + w * 512);
    __syncthreads();
    short8 af[4], bfv[4];
#pragma unroll
    for (int mi = 0; mi < 4; ++mi)
      af[mi] = *(const short8*)&lsA[(wm + mi * 16 + r15) * 32 + g * 8];
#pragma unroll
    for (int ni = 0; ni < 4; ++ni)
      bfv[ni] = *(const short8*)&lsB[(wn + ni * 16 + r15) * 32 + g * 8];
#pragma unroll
    for (int mi = 0; mi < 4; ++mi)
#pragma unroll
      for (int ni = 0; ni < 4; ++ni)
        acc[mi][ni] = __builtin_amdgcn_mfma_f32_16x16x32_bf16(af[mi], bfv[ni], acc[mi][ni], 0, 0, 0);
    __syncthreads();
  }

#pragma unroll
  for (int mi = 0; mi < 4; ++mi)
#pragma unroll
    for (int ni = 0; ni < 4; ++ni)
#pragma unroll
      for (int r = 0; r < 4; ++r) {
        int row = m0 + wm + mi * 16 + g * 4 + r;   // D: row=(l>>4)*4+reg
        int col = n0 + wn + ni * 16 + r15;         //    col=l&15
        float v = acc[mi][ni][r];
        if (EPI == 0) {
          ((u16*)outp)[(((size_t)(row >> 11) * 16 + (col >> 6)) * SEQ + (row & 2047)) * 64 + (col & 63)] = f2bf(v * oscale);
        } else if (EPI == 1) {
          ((u16*)outp)[(((size_t)(row >> 11) * 16 + (col >> 6)) * 64 + (col & 63)) * SEQ + (row & 2047)] = f2bf(v);
        } else {
          ((float*)outp)[(size_t)row * EMBED + col] = v + bias[col];
        }
      }
}

// ---------------- flash attention (swapped-operand, k lane-local) ----------------
// Q, K: [bh=64][S=2048][64] bf16 (Q pre-scaled by log2e/sqrt(1024));
// Vt: [bh][64][S] bf16 ; out AO: [n][s][1024] bf16
// Per block: 4 waves x 32 q-rows = 128 q. Per KV tile (64 rows):
//   S^T = mfma(K, Q)  -> lane holds S[k = c*16+g*4+r][q = qi*16+(l&15)]
//   row-max: 15 in-lane fmax + shfl_xor(16,32); row-sum: per-lane partial, reduced once at end
//   PV: O^T = V^T P^T with k-permutation pi(g,j)=kh*32+(j>=4)*16+4g+(j&3) applied to BOTH
//   the P B-frag (built from own regs via cvt_pk, no shuffles/LDS) and V^T A-frag columns.
__global__ __launch_bounds__(256) void attn_kernel(const u16* __restrict__ Q,
                                                   const u16* __restrict__ Kb,
                                                   const u16* __restrict__ Vt,
                                                   u16* __restrict__ AO) {
  __shared__ u16 lsK[2][64 * 64];
  __shared__ u16 lsV[2][64 * 64];
  const int t = threadIdx.x, l = t & 63, w = t >> 6;
  const int g = l >> 4, r15 = l & 15;

  // XCD-bijective remap: 1024 blocks = 8 XCDs x 128; each XCD owns 8 whole heads
  const int flat = blockIdx.x;
  const int work = (flat & 7) * 128 + (flat >> 3);
  const int bh = work >> 4;
  const int q0 = (work & 15) * 128;

  const u16* Qh = Q + (size_t)bh * SEQ * 64;
  const u16* Kh = Kb + (size_t)bh * SEQ * 64;
  const u16* Vh = Vt + (size_t)bh * 64 * SEQ;

  short8 qf[2][2];
#pragma unroll
  for (int qi = 0; qi < 2; ++qi)
#pragma unroll
    for (int dh = 0; dh < 2; ++dh)
      qf[qi][dh] = *(const short8*)&Qh[(size_t)(q0 + w * 32 + qi * 16 + r15) * 64 + dh * 32 + g * 8];

  float mrun[2] = { -1e30f, -1e30f }, lsum[2] = { 0.f, 0.f };
  f32x4 oacc[4][2] = {};

  const int srow = t >> 3;         // 0..31
  const int scolb = (t & 7) * 16;  // byte col within 128B row

  auto STAGE = [&](int buf, int kv0) {
#pragma unroll
    for (int j = 0; j < 2; ++j) {
      int row = j * 32 + srow;
      int colswz = (scolb ^ ((row & 7) << 4)) >> 1;  // pre-swizzled source (elems)
      gld16(Kh + (size_t)(kv0 + row) * 64 + colswz, &lsK[buf][j * 2048 + w * 512]);
      gld16(Vh + (size_t)row * SEQ + kv0 + colswz,  &lsV[buf][j * 2048 + w * 512]);
    }
  };

  STAGE(0, 0);
  asm volatile("s_waitcnt vmcnt(0)" ::: "memory");
  __builtin_amdgcn_s_barrier();

  int cur = 0;
  for (int kv = 0; kv < SEQ / 64; ++kv) {
    if (kv + 1 < SEQ / 64) STAGE(cur ^ 1, (kv + 1) * 64);

    const u16* Kc = lsK[cur];
    const u16* Vc = lsV[cur];

    // ---- S^T = K Q^T (swapped) ----
    f32x4 sacc[2][4] = {};
#pragma unroll
    for (int c = 0; c < 4; ++c) {
      int krow = c * 16 + r15;
      int sz = (krow & 7) << 4;
#pragma unroll
      for (int dh = 0; dh < 2; ++dh) {
        short8 kf = *(const short8*)((const char*)Kc + krow * 128 + ((dh * 64 + g * 16) ^ sz));
#pragma unroll
        for (int qi = 0; qi < 2; ++qi)
          sacc[qi][c] = __builtin_amdgcn_mfma_f32_16x16x32_bf16(kf, qf[qi][dh], sacc[qi][c], 0, 0, 0);
      }
    }

    // ---- row max (k lane-local) ----
    float mt[2];
#pragma unroll
    for (int qi = 0; qi < 2; ++qi) {
      float m = sacc[qi][0][0];
#pragma unroll
      for (int c = 0; c < 4; ++c)
#pragma unroll
        for (int r = 0; r < 4; ++r)
          m = fmaxf(m, sacc[qi][c][r]);
      m = fmaxf(m, __shfl_xor(m, 16, 64));
      m = fmaxf(m, __shfl_xor(m, 32, 64));
      mt[qi] = m;
    }

    // ---- defer-max rescale (THR = 8 in log2 domain) ----
    int ok = (mt[0] <= mrun[0] + 8.f) && (mt[1] <= mrun[1] + 8.f);
    if (!__all(ok)) {
#pragma unroll
      for (int qi = 0; qi < 2; ++qi) {
        float mn = fmaxf(mrun[qi], mt[qi]);
        float al = exp2a(mrun[qi] - mn);
        mrun[qi] = mn;
        lsum[qi] *= al;
#pragma unroll
        for (int dc = 0; dc < 4; ++dc)
#pragma unroll
          for (int r = 0; r < 4; ++r)
            oacc[dc][qi][r] *= al;
      }
    }

    // ---- p = 2^(s-m), per-lane partial sum, pack P B-frags from own regs ----
    short8 pb[2][2];
#pragma unroll
    for (int qi = 0; qi < 2; ++qi) {
      float s0 = 0.f;
#pragma unroll
      for (int c = 0; c < 4; ++c)
#pragma unroll
        for (int r = 0; r < 4; ++r) {
          float p = exp2a(sacc[qi][c][r] - mrun[qi]);
          sacc[qi][c][r] = p;
          s0 += p;
        }
      lsum[qi] += s0;
#pragma unroll
      for (int kh = 0; kh < 2; ++kh) {
        union { uint32_t u[4]; short8 s; } pu;
        pu.u[0] = cvtpk(sacc[qi][2 * kh][0],     sacc[qi][2 * kh][1]);
        pu.u[1] = cvtpk(sacc[qi][2 * kh][2],     sacc[qi][2 * kh][3]);
        pu.u[2] = cvtpk(sacc[qi][2 * kh + 1][0], sacc[qi][2 * kh + 1][1]);
        pu.u[3] = cvtpk(sacc[qi][2 * kh + 1][2], sacc[qi][2 * kh + 1][3]);
        pb[qi][kh] = pu.s;
      }
    }

    // ---- O^T += V^T P^T (permuted-k A-frag: two b64 reads per frag) ----
#pragma unroll
    for (int dc = 0; dc < 4; ++dc) {
      int vrow = dc * 16 + r15;
      int sz = (vrow & 7) << 4;
      const char* vb = (const char*)Vc + vrow * 128;
#pragma unroll
      for (int kh = 0; kh < 2; ++kh) {
        union { uint2 v[2]; short8 s; } va;
        va.v[0] = *(const uint2*)(vb + ((kh * 64 + 8 * g) ^ sz));
        va.v[1] = *(const uint2*)(vb + ((kh * 64 + 32 + 8 * g) ^ sz));
#pragma unroll
        for (int qi = 0; qi < 2; ++qi)
          oacc[dc][qi] = __builtin_amdgcn_mfma_f32_16x16x32_bf16(va.s, pb[qi][kh], oacc[dc][qi], 0, 0, 0);
      }
    }

    asm volatile("s_waitcnt vmcnt(0)" ::: "memory");
    __builtin_amdgcn_s_barrier();
    cur ^= 1;
  }

  // ---- final row-sum reduce (once) + normalized packed write ----
  const int nb = bh >> 4, h = bh & 15;
#pragma unroll
  for (int qi = 0; qi < 2; ++qi) {
    float s = lsum[qi];
    s += __shfl_xor(s, 16, 64);
    s += __shfl_xor(s, 32, 64);
    lsum[qi] = 1.0f / s;
  }
#pragma unroll
  for (int dc = 0; dc < 4; ++dc)
#pragma unroll
    for (int qi = 0; qi < 2; ++qi) {
      int q = q0 + w * 32 + qi * 16 + r15;
      int d = dc * 16 + g * 4;
      uint32_t a = cvtpk(oacc[dc][qi][0] * lsum[qi], oacc[dc][qi][1] * lsum[qi]);
      uint32_t b = cvtpk(oacc[dc][qi][2] * lsum[qi], oacc[dc][qi][3] * lsum[qi]);
      uint2* dst = (uint2*)&AO[((size_t)(nb * SEQ + q)) * EMBED + h * 64 + d];
      *dst = make_uint2(a, b);
    }
}

// ---------------- launch ----------------
extern "C" void kernel_launch(void* const* d_in, const int* in_sizes, int n_in,
                              void* d_out, int out_size, void* d_ws, size_t ws_size,
                              hipStream_t stream) {
  const float* values  = (const float*)d_in[0];
  const float* keys    = (const float*)d_in[1];
  const float* queries = (const float*)d_in[2];
  const float* W_v = (const float*)d_in[3];
  const float* W_k = (const float*)d_in[4];
  const float* W_q = (const float*)d_in[5];
  const float* W_o = (const float*)d_in[6];
  const float* b_o = (const float*)d_in[7];

  const size_t XSZ = (size_t)MROWS * EMBED;  // 8,388,608 elems
  const size_t WSZ = (size_t)EMBED * EMBED;  // 1,048,576 elems
  u16* ws = (u16*)d_ws;
  u16* Xv  = ws;
  u16* Xk  = ws + XSZ;
  u16* Xq  = ws + 2 * XSZ;
  u16* Wvt = ws + 3 * XSZ;
  u16* Wkt = Wvt + WSZ;
  u16* Wqt = Wkt + WSZ;
  u16* Wot = Wqt + WSZ;
  u16* Qb  = Wot + WSZ;
  u16* Kb  = Qb + XSZ;
  u16* Vtb = Kb + XSZ;
  u16* AO  = Xv;  // alias: Xv dead after V projection

  int n4 = (int)(XSZ / 4);
  cvt_bf16_kernel<<<1024, 256, 0, stream>>>((const float4*)values,  (u16x4*)Xv, n4);
  cvt_bf16_kernel<<<1024, 256, 0, stream>>>((const float4*)keys,    (u16x4*)Xk, n4);
  cvt_bf16_kernel<<<1024, 256, 0, stream>>>((const float4*)queries, (u16x4*)Xq, n4);

  dim3 tg(32, 32);
  wtrans_kernel<<<tg, 256, 0, stream>>>(W_v, Wvt);
  wtrans_kernel<<<tg, 256, 0, stream>>>(W_k, Wkt);
  wtrans_kernel<<<tg, 256, 0, stream>>>(W_q, Wqt);
  wtrans_kernel<<<tg, 256, 0, stream>>>(W_o, Wot);

  // fold softmax scale (1/sqrt(1024)) and log2(e) into Q so attention uses exp2 directly
  const float QSCALE = 0.03125f * 1.4426950408889634f;
  dim3 gg(EMBED / 128, MROWS / 128);  // 8 x 64
  gemm_bt<0><<<gg, 256, 0, stream>>>(Xq, Wqt, Qb, nullptr, QSCALE);
  gemm_bt<0><<<gg, 256, 0, stream>>>(Xk, Wkt, Kb, nullptr, 1.0f);
  gemm_bt<1><<<gg, 256, 0, stream>>>(Xv, Wvt, Vtb, nullptr, 1.0f);

  attn_kernel<<<1024, 256, 0, stream>>>(Qb, Kb, Vtb, AO);

  gemm_bt<2><<<gg, 256, 0, stream>>>(AO, Wot, d_out, b_o, 1.0f);
}

// Round 4
// 251.599 us; speedup vs baseline: 1.4414x; 1.0630x over previous
//
#include <hip/hip_runtime.h>
#include <hip/hip_bf16.h>
#include <stdint.h>

typedef __attribute__((ext_vector_type(8))) short short8;
typedef __attribute__((ext_vector_type(4))) float f32x4;
typedef __attribute__((ext_vector_type(4))) unsigned short u16x4;
typedef unsigned short u16;

#define EMBED 1024
#define SEQ 2048
#define NBATCH 4
#define MROWS (NBATCH * SEQ) /* 8192 */

__device__ __forceinline__ u16 f2bf(float f) {
  union { float f; uint32_t u; } v; v.f = f;
  uint32_t r = v.u + 0x7fffu + ((v.u >> 16) & 1u);
  return (u16)(r >> 16);
}

__device__ __forceinline__ uint32_t cvtpk(float lo, float hi) {
  uint32_t r;
  asm("v_cvt_pk_bf16_f32 %0, %1, %2" : "=v"(r) : "v"(lo), "v"(hi));
  return r;
}

__device__ __forceinline__ float exp2a(float x) {
#if __has_builtin(__builtin_amdgcn_exp2f)
  return __builtin_amdgcn_exp2f(x);
#else
  return exp2f(x);
#endif
}

__device__ __forceinline__ void gld16(const void* g, void* l) {
  __builtin_amdgcn_global_load_lds((const __attribute__((address_space(1))) void*)g,
                                   (__attribute__((address_space(3))) void*)l, 16, 0, 0);
}

// ---------------- fp32 -> bf16 convert (vectorized) ----------------
__global__ __launch_bounds__(256) void cvt_bf16_kernel(const float4* __restrict__ in,
                                                       u16x4* __restrict__ out, int n4) {
  int stride = gridDim.x * blockDim.x;
  for (int i = blockIdx.x * blockDim.x + threadIdx.x; i < n4; i += stride) {
    float4 v = in[i];
    u16x4 o = { f2bf(v.x), f2bf(v.y), f2bf(v.z), f2bf(v.w) };
    out[i] = o;
  }
}

// ---------------- W [k][n] fp32 -> W^T [n][k] bf16 ----------------
__global__ __launch_bounds__(256) void wtrans_kernel(const float* __restrict__ W,
                                                     u16* __restrict__ Wt) {
  __shared__ float tile[32][33];
  int bx = blockIdx.x * 32, by = blockIdx.y * 32;
  int tx = threadIdx.x & 31, ty = threadIdx.x >> 5; // 32 x 8
#pragma unroll
  for (int i = 0; i < 32; i += 8)
    tile[ty + i][tx] = W[(size_t)(by + ty + i) * EMBED + bx + tx];
  __syncthreads();
#pragma unroll
  for (int i = 0; i < 32; i += 8)
    Wt[(size_t)(bx + ty + i) * EMBED + by + tx] = f2bf(tile[tx][ty + i]);
}

// ---------------- GEMM: C[M=8192][N=1024] = A[M][K=1024] * Bt[N][K]^T ----------------
// BK=64 (32 MFMA per barrier pair), T2 XOR-swizzled LDS (pre-swizzled gld16 source
// + swizzled ds_read_b128: byte ^= (row&7)<<4 within each 128B row).
// EPI 0: bf16 out *oscale, NHSD scatter ([n][h][s][d])   (Q, K)
// EPI 1: bf16 out, NHDS scatter ([n][h][d][s])           (V transposed)
// EPI 2: fp32 out row-major + bias                       (final projection)
template <int EPI>
__global__ __launch_bounds__(256) void gemm_bt(const u16* __restrict__ A,
                                               const u16* __restrict__ Bt,
                                               void* __restrict__ outp,
                                               const float* __restrict__ bias,
                                               float oscale) {
  constexpr int K = 1024;
  __shared__ u16 lsA[128 * 64];
  __shared__ u16 lsB[128 * 64];
  const int t = threadIdx.x, l = t & 63, w = t >> 6;
  const int g = l >> 4, r15 = l & 15;
  const int m0 = blockIdx.y * 128, n0 = blockIdx.x * 128;
  const int wm = (w >> 1) * 64, wn = (w & 1) * 64;
  f32x4 acc[4][4] = {};
  const int srow = t >> 3;        // 0..31
  const int sc16 = (t & 7) * 16;  // byte chunk within 128B k-row

  const u16* Ap[4]; const u16* Bp[4];
#pragma unroll
  for (int j = 0; j < 4; ++j) {
    int row = srow + j * 32;
    int colswz = (sc16 ^ ((row & 7) << 4)) >> 1;  // pre-swizzled source col (elems)
    Ap[j] = A  + (size_t)(m0 + row) * K + colswz;
    Bp[j] = Bt + (size_t)(n0 + row) * K + colswz;
  }

  for (int k0 = 0; k0 < K; k0 += 64) {
#pragma unroll
    for (int j = 0; j < 4; ++j) {
      gld16(Ap[j] + k0, lsA + j * 2048 + w * 512);
      gld16(Bp[j] + k0, lsB + j * 2048 + w * 512);
    }
    __syncthreads();
    short8 af[2][4], bfv[2][4];
#pragma unroll
    for (int kk = 0; kk < 2; ++kk) {
#pragma unroll
      for (int mi = 0; mi < 4; ++mi) {
        int row = wm + mi * 16 + r15;
        af[kk][mi] = *(const short8*)((const char*)lsA + row * 128 + ((kk * 64 + g * 16) ^ ((row & 7) << 4)));
      }
#pragma unroll
      for (int ni = 0; ni < 4; ++ni) {
        int row = wn + ni * 16 + r15;
        bfv[kk][ni] = *(const short8*)((const char*)lsB + row * 128 + ((kk * 64 + g * 16) ^ ((row & 7) << 4)));
      }
    }
#pragma unroll
    for (int kk = 0; kk < 2; ++kk)
#pragma unroll
      for (int mi = 0; mi < 4; ++mi)
#pragma unroll
        for (int ni = 0; ni < 4; ++ni)
          acc[mi][ni] = __builtin_amdgcn_mfma_f32_16x16x32_bf16(af[kk][mi], bfv[kk][ni], acc[mi][ni], 0, 0, 0);
    __syncthreads();
  }

#pragma unroll
  for (int mi = 0; mi < 4; ++mi)
#pragma unroll
    for (int ni = 0; ni < 4; ++ni)
#pragma unroll
      for (int r = 0; r < 4; ++r) {
        int row = m0 + wm + mi * 16 + g * 4 + r;   // D: row=(l>>4)*4+reg
        int col = n0 + wn + ni * 16 + r15;         //    col=l&15
        float v = acc[mi][ni][r];
        if (EPI == 0) {
          ((u16*)outp)[(((size_t)(row >> 11) * 16 + (col >> 6)) * SEQ + (row & 2047)) * 64 + (col & 63)] = f2bf(v * oscale);
        } else if (EPI == 1) {
          ((u16*)outp)[(((size_t)(row >> 11) * 16 + (col >> 6)) * 64 + (col & 63)) * SEQ + (row & 2047)] = f2bf(v);
        } else {
          ((float*)outp)[(size_t)row * EMBED + col] = v + bias[col];
        }
      }
}

// ---------------- flash attention (swapped-operand, k lane-local) ----------------
// Q, K: [bh=64][S=2048][64] bf16 (Q pre-scaled by log2e/sqrt(1024));
// Vt: [bh][64][S] bf16 ; out AO: [n][s][1024] bf16
// K staged via gld16 (16B-granular swizzle c4=(row&7)<<4, b128 reads conflict-free).
// V reg-staged (T14): global->reg early, swizzled ds_write_b64 late with
// c = c4 | ((row>>3)&1)<<3 so the 16 lanes of each b64-read phase cover all 32 banks.
__global__ __launch_bounds__(256) void attn_kernel(const u16* __restrict__ Q,
                                                   const u16* __restrict__ Kb,
                                                   const u16* __restrict__ Vt,
                                                   u16* __restrict__ AO) {
  __shared__ u16 lsK[2][64 * 64];
  __shared__ u16 lsV[2][64 * 64];
  const int t = threadIdx.x, l = t & 63, w = t >> 6;
  const int g = l >> 4, r15 = l & 15;

  // XCD-bijective remap: 1024 blocks = 8 XCDs x 128; each XCD owns 8 whole heads
  const int flat = blockIdx.x;
  const int work = (flat & 7) * 128 + (flat >> 3);
  const int bh = work >> 4;
  const int q0 = (work & 15) * 128;

  const u16* Qh = Q + (size_t)bh * SEQ * 64;
  const u16* Kh = Kb + (size_t)bh * SEQ * 64;
  const u16* Vh = Vt + (size_t)bh * 64 * SEQ;

  short8 qf[2][2];
#pragma unroll
  for (int qi = 0; qi < 2; ++qi)
#pragma unroll
    for (int dh = 0; dh < 2; ++dh)
      qf[qi][dh] = *(const short8*)&Qh[(size_t)(q0 + w * 32 + qi * 16 + r15) * 64 + dh * 32 + g * 8];

  float mrun[2] = { -1e30f, -1e30f }, lsum[2] = { 0.f, 0.f };
  f32x4 oacc[4][2] = {};

  const int srow = t >> 3;         // 0..31
  const int scolb = (t & 7) * 16;  // byte col within 128B row

  uint4 vreg[2];

  auto STAGE_K = [&](int buf, int kv0) {
#pragma unroll
    for (int j = 0; j < 2; ++j) {
      int row = j * 32 + srow;
      int colswz = (scolb ^ ((row & 7) << 4)) >> 1;
      gld16(Kh + (size_t)(kv0 + row) * 64 + colswz, &lsK[buf][j * 2048 + w * 512]);
    }
  };
  auto VLOAD = [&](int kv0) {
#pragma unroll
    for (int j = 0; j < 2; ++j) {
      int row = j * 32 + srow;  // d-row of V^T
      vreg[j] = *(const uint4*)(Vh + (size_t)row * SEQ + kv0 + (scolb >> 1));
    }
  };
  auto VSTORE = [&](int buf) {
#pragma unroll
    for (int j = 0; j < 2; ++j) {
      int row = j * 32 + srow;
      int c4 = (row & 7) << 4, c3 = ((row >> 3) & 1) << 3;
      char* base = (char*)&lsV[buf][0] + row * 128 + (scolb ^ c4);
      *(uint2*)(base + c3)       = make_uint2(vreg[j].x, vreg[j].y);
      *(uint2*)(base + (8 ^ c3)) = make_uint2(vreg[j].z, vreg[j].w);
    }
  };

  VLOAD(0);
  STAGE_K(0, 0);
  VSTORE(0);  // compiler inserts the vmcnt wait for vreg
  asm volatile("s_waitcnt vmcnt(0) lgkmcnt(0)" ::: "memory");
  __builtin_amdgcn_s_barrier();

  int cur = 0;
  for (int kv = 0; kv < SEQ / 64; ++kv) {
    const bool more = (kv + 1 < SEQ / 64);
    if (more) {
      VLOAD((kv + 1) * 64);
      STAGE_K(cur ^ 1, (kv + 1) * 64);
    }

    const u16* Kc = lsK[cur];
    const u16* Vc = lsV[cur];

    // ---- S^T = K Q^T (swapped) ----
    f32x4 sacc[2][4] = {};
    __builtin_amdgcn_s_setprio(1);
#pragma unroll
    for (int c = 0; c < 4; ++c) {
      int krow = c * 16 + r15;
      int sz = (krow & 7) << 4;
#pragma unroll
      for (int dh = 0; dh < 2; ++dh) {
        short8 kf = *(const short8*)((const char*)Kc + krow * 128 + ((dh * 64 + g * 16) ^ sz));
#pragma unroll
        for (int qi = 0; qi < 2; ++qi)
          sacc[qi][c] = __builtin_amdgcn_mfma_f32_16x16x32_bf16(kf, qf[qi][dh], sacc[qi][c], 0, 0, 0);
      }
    }
    __builtin_amdgcn_s_setprio(0);

    // ---- row max (k lane-local, max3 trees) ----
    float mt[2];
#pragma unroll
    for (int qi = 0; qi < 2; ++qi) {
      const f32x4* s = sacc[qi];
      float t0 = fmaxf(fmaxf(s[0][0], s[0][1]), s[0][2]);
      float t1 = fmaxf(fmaxf(s[0][3], s[1][0]), s[1][1]);
      float t2 = fmaxf(fmaxf(s[1][2], s[1][3]), s[2][0]);
      float t3 = fmaxf(fmaxf(s[2][1], s[2][2]), s[2][3]);
      float t4 = fmaxf(fmaxf(s[3][0], s[3][1]), s[3][2]);
      float m = fmaxf(fmaxf(t0, t1), fmaxf(fmaxf(t2, t3), fmaxf(t4, s[3][3])));
      m = fmaxf(m, __shfl_xor(m, 16, 64));
      m = fmaxf(m, __shfl_xor(m, 32, 64));
      mt[qi] = m;
    }

    // ---- defer-max rescale (THR = 8 in log2 domain) ----
    int ok = (mt[0] <= mrun[0] + 8.f) && (mt[1] <= mrun[1] + 8.f);
    if (!__all(ok)) {
#pragma unroll
      for (int qi = 0; qi < 2; ++qi) {
        float mn = fmaxf(mrun[qi], mt[qi]);
        float al = exp2a(mrun[qi] - mn);
        mrun[qi] = mn;
        lsum[qi] *= al;
#pragma unroll
        for (int dc = 0; dc < 4; ++dc)
#pragma unroll
          for (int r = 0; r < 4; ++r)
            oacc[dc][qi][r] *= al;
      }
    }

    // ---- p = 2^(s-m), per-lane partial sum, pack P B-frags from own regs ----
    short8 pb[2][2];
#pragma unroll
    for (int qi = 0; qi < 2; ++qi) {
      float s0 = 0.f;
#pragma unroll
      for (int c = 0; c < 4; ++c)
#pragma unroll
        for (int r = 0; r < 4; ++r) {
          float p = exp2a(sacc[qi][c][r] - mrun[qi]);
          sacc[qi][c][r] = p;
          s0 += p;
        }
      lsum[qi] += s0;
#pragma unroll
      for (int kh = 0; kh < 2; ++kh) {
        union { uint32_t u[4]; short8 s; } pu;
        pu.u[0] = cvtpk(sacc[qi][2 * kh][0],     sacc[qi][2 * kh][1]);
        pu.u[1] = cvtpk(sacc[qi][2 * kh][2],     sacc[qi][2 * kh][3]);
        pu.u[2] = cvtpk(sacc[qi][2 * kh + 1][0], sacc[qi][2 * kh + 1][1]);
        pu.u[3] = cvtpk(sacc[qi][2 * kh + 1][2], sacc[qi][2 * kh + 1][3]);
        pb[qi][kh] = pu.s;
      }
    }

    // ---- O^T += V^T P^T (permuted-k A-frag: two b64 reads per frag) ----
    __builtin_amdgcn_s_setprio(1);
#pragma unroll
    for (int dc = 0; dc < 4; ++dc) {
      int vrow = dc * 16 + r15;
      int sz = ((vrow & 7) << 4) | (((vrow >> 3) & 1) << 3);
      const char* vb = (const char*)Vc + vrow * 128;
#pragma unroll
      for (int kh = 0; kh < 2; ++kh) {
        union { uint2 v[2]; short8 s; } va;
        va.v[0] = *(const uint2*)(vb + ((kh * 64 + 8 * g) ^ sz));
        va.v[1] = *(const uint2*)(vb + ((kh * 64 + 32 + 8 * g) ^ sz));
#pragma unroll
        for (int qi = 0; qi < 2; ++qi)
          oacc[dc][qi] = __builtin_amdgcn_mfma_f32_16x16x32_bf16(va.s, pb[qi][kh], oacc[dc][qi], 0, 0, 0);
      }
    }
    __builtin_amdgcn_s_setprio(0);

    if (more) VSTORE(cur ^ 1);  // vreg use -> compiler-inserted vmcnt wait
    asm volatile("s_waitcnt vmcnt(0) lgkmcnt(0)" ::: "memory");
    __builtin_amdgcn_s_barrier();
    cur ^= 1;
  }

  // ---- final row-sum reduce (once) + normalized packed write ----
  const int nb = bh >> 4, h = bh & 15;
#pragma unroll
  for (int qi = 0; qi < 2; ++qi) {
    float s = lsum[qi];
    s += __shfl_xor(s, 16, 64);
    s += __shfl_xor(s, 32, 64);
    lsum[qi] = 1.0f / s;
  }
#pragma unroll
  for (int dc = 0; dc < 4; ++dc)
#pragma unroll
    for (int qi = 0; qi < 2; ++qi) {
      int q = q0 + w * 32 + qi * 16 + r15;
      int d = dc * 16 + g * 4;
      uint32_t a = cvtpk(oacc[dc][qi][0] * lsum[qi], oacc[dc][qi][1] * lsum[qi]);
      uint32_t b = cvtpk(oacc[dc][qi][2] * lsum[qi], oacc[dc][qi][3] * lsum[qi]);
      uint2* dst = (uint2*)&AO[((size_t)(nb * SEQ + q)) * EMBED + h * 64 + d];
      *dst = make_uint2(a, b);
    }
}

// ---------------- launch ----------------
extern "C" void kernel_launch(void* const* d_in, const int* in_sizes, int n_in,
                              void* d_out, int out_size, void* d_ws, size_t ws_size,
                              hipStream_t stream) {
  const float* values  = (const float*)d_in[0];
  const float* keys    = (const float*)d_in[1];
  const float* queries = (const float*)d_in[2];
  const float* W_v = (const float*)d_in[3];
  const float* W_k = (const float*)d_in[4];
  const float* W_q = (const float*)d_in[5];
  const float* W_o = (const float*)d_in[6];
  const float* b_o = (const float*)d_in[7];

  const size_t XSZ = (size_t)MROWS * EMBED;  // 8,388,608 elems
  const size_t WSZ = (size_t)EMBED * EMBED;  // 1,048,576 elems
  u16* ws = (u16*)d_ws;
  u16* Xv  = ws;
  u16* Xk  = ws + XSZ;
  u16* Xq  = ws + 2 * XSZ;
  u16* Wvt = ws + 3 * XSZ;
  u16* Wkt = Wvt + WSZ;
  u16* Wqt = Wkt + WSZ;
  u16* Wot = Wqt + WSZ;
  u16* Qb  = Wot + WSZ;
  u16* Kb  = Qb + XSZ;
  u16* Vtb = Kb + XSZ;
  u16* AO  = Xv;  // alias: Xv dead after V projection

  int n4 = (int)(XSZ / 4);
  cvt_bf16_kernel<<<1024, 256, 0, stream>>>((const float4*)values,  (u16x4*)Xv, n4);
  cvt_bf16_kernel<<<1024, 256, 0, stream>>>((const float4*)keys,    (u16x4*)Xk, n4);
  cvt_bf16_kernel<<<1024, 256, 0, stream>>>((const float4*)queries, (u16x4*)Xq, n4);

  dim3 tg(32, 32);
  wtrans_kernel<<<tg, 256, 0, stream>>>(W_v, Wvt);
  wtrans_kernel<<<tg, 256, 0, stream>>>(W_k, Wkt);
  wtrans_kernel<<<tg, 256, 0, stream>>>(W_q, Wqt);
  wtrans_kernel<<<tg, 256, 0, stream>>>(W_o, Wot);

  // fold softmax scale (1/sqrt(1024)) and log2(e) into Q so attention uses exp2 directly
  const float QSCALE = 0.03125f * 1.4426950408889634f;
  dim3 gg(EMBED / 128, MROWS / 128);  // 8 x 64
  gemm_bt<0><<<gg, 256, 0, stream>>>(Xq, Wqt, Qb, nullptr, QSCALE);
  gemm_bt<0><<<gg, 256, 0, stream>>>(Xk, Wkt, Kb, nullptr, 1.0f);
  gemm_bt<1><<<gg, 256, 0, stream>>>(Xv, Wvt, Vtb, nullptr, 1.0f);

  attn_kernel<<<1024, 256, 0, stream>>>(Qb, Kb, Vtb, AO);

  gemm_bt<2><<<gg, 256, 0, stream>>>(AO, Wot, d_out, b_o, 1.0f);
}